// Round 6
// baseline (275.411 us; speedup 1.0000x reference)
//
#include <hip/hip_runtime.h>

// nw_out [N=4, C=19, H=512, W=1024] fp32; output: 1 fp32 scalar.
#define N_IMG 4
#define C_CLS 19
#define HW    (512 * 1024)          // per-channel plane (floats)
#define NPIX  (N_IMG * HW)          // 2,097,152 pixels
#define NBLK  4096                  // 256 thr x 2 px each
#define IW    0.2f

typedef float f2 __attribute__((ext_vector_type(2)));

// ---------------------------------------------------------------------------
// main_pass: plain cached loads + ONLINE softmax-square so every channel value
// is consumed exactly once (compiler cannot re-load; tiny live set -> it
// hoists load batches up to the 128-VGPR budget = real MLP at ~16 waves/CU).
// Per pixel: running max m, l=sum e^(x-m), q=sum e^(2(x-m)), argmax am.
// Per-class sums/counts in lane-local registers; unique-slot partials.
// ---------------------------------------------------------------------------
__global__ __launch_bounds__(256, 4) void main_pass(const float* __restrict__ x,
                                                    float* __restrict__ part) {
    __shared__ float s_bins[4][2 * C_CLS];
    const int t = threadIdx.x, lane = t & 63, wave = t >> 6;
    const int b = blockIdx.x;

    // float2 pixel-pair index; grid exactly covers NPIX/2 (4096 * 256).
    const int v   = b * 256 + t;
    const int n   = v >> 18;                 // HW/2 = 262144 = 2^18
    const int hw2 = v & (262144 - 1);
    const float* base = x + (size_t)n * C_CLS * HW + (size_t)hw2 * 2;

    float asum[C_CLS], acnt[C_CLS];
#pragma unroll
    for (int c = 0; c < C_CLS; ++c) { asum[c] = 0.0f; acnt[c] = 0.0f; }

    // ---- online pass over channels, 2 pixels per thread ----
    float m0, l0, q0, m1, l1, q1;
    int   am0 = 0, am1 = 0;
    {
        f2 x0 = *(const f2*)base;
        m0 = x0[0]; l0 = 1.0f; q0 = 1.0f;
        m1 = x0[1]; l1 = 1.0f; q1 = 1.0f;
    }
#pragma unroll
    for (int c = 1; c < C_CLS; ++c) {
        f2 xc = *(const f2*)(base + (size_t)c * HW);
        {   // pixel 0
            float xv = xc[0];
            float mn = fmaxf(m0, xv);
            float sc = __expf(m0 - mn);      // ==1 unless new max
            float e  = __expf(xv - mn);      // ==1 if new max
            l0 = l0 * sc + e;
            q0 = q0 * (sc * sc) + e * e;
            am0 = (xv > m0) ? c : am0;       // strict > = first-max (jnp.argmax)
            m0 = mn;
        }
        {   // pixel 1
            float xv = xc[1];
            float mn = fmaxf(m1, xv);
            float sc = __expf(m1 - mn);
            float e  = __expf(xv - mn);
            l1 = l1 * sc + e;
            q1 = q1 * (sc * sc) + e * e;
            am1 = (xv > m1) ? c : am1;
            m1 = mn;
        }
    }
    float s0 = q0 * __builtin_amdgcn_rcpf(l0 * l0);  // sum(prob^2), px0
    float s1 = q1 * __builtin_amdgcn_rcpf(l1 * l1);  // sum(prob^2), px1

#pragma unroll
    for (int c = 0; c < C_CLS; ++c) {                // register bins
        bool h0 = (am0 == c), h1 = (am1 == c);
        asum[c] += (h0 ? s0 : 0.0f) + (h1 ? s1 : 0.0f);
        acnt[c] += (h0 ? 1.0f : 0.0f) + (h1 ? 1.0f : 0.0f);
    }

    // ---- wave-reduce the 38 accumulators, then block-combine via LDS ----
#pragma unroll
    for (int c = 0; c < C_CLS; ++c) {
        float a = asum[c], k = acnt[c];
        for (int off = 32; off > 0; off >>= 1) {
            a += __shfl_down(a, off);
            k += __shfl_down(k, off);
        }
        if (lane == 0) { s_bins[wave][c] = a; s_bins[wave][C_CLS + c] = k; }
    }
    __syncthreads();
    if (t < 2 * C_CLS) {                             // unique slots, no atomics
        float a = s_bins[0][t] + s_bins[1][t] + s_bins[2][t] + s_bins[3][t];
        part[(size_t)t * NBLK + b] = a;
    }
}

// ---------------------------------------------------------------------------
// finalize: reduce [38][4096] partials; den_c = max(cnt^0.2 * Np^0.8, 1);
// out = -sum_c(sum_c/den_c) / (N*C).
// ---------------------------------------------------------------------------
__global__ __launch_bounds__(1024) void finalize(const float* __restrict__ part,
                                                 float* __restrict__ out) {
    __shared__ float sval[2 * C_CLS];
    const int wave = threadIdx.x >> 6, lane = threadIdx.x & 63;

    for (int v = wave; v < 2 * C_CLS; v += 16) {
        const float* row = part + (size_t)v * NBLK;
        float a = 0.0f;
        for (int i = lane; i < NBLK; i += 64) a += row[i];
#pragma unroll
        for (int off = 32; off > 0; off >>= 1) a += __shfl_down(a, off);
        if (lane == 0) sval[v] = a;
    }
    __syncthreads();

    if (threadIdx.x < 64) {
        float vsum = 0.0f;
        if (threadIdx.x < C_CLS) {
            float sum = sval[threadIdx.x];
            float cnt = sval[C_CLS + threadIdx.x];
            const float scale = powf((float)NPIX, 1.0f - IW);   // Np^0.8
            float den = fmaxf(powf(cnt, IW) * scale, 1.0f);
            vsum = sum / den;
        }
#pragma unroll
        for (int off = 32; off > 0; off >>= 1) vsum += __shfl_down(vsum, off);
        if (threadIdx.x == 0)
            out[0] = -vsum / (float)(N_IMG * C_CLS);
    }
}

extern "C" void kernel_launch(void* const* d_in, const int* in_sizes, int n_in,
                              void* d_out, int out_size, void* d_ws, size_t ws_size,
                              hipStream_t stream) {
    const float* x = (const float*)d_in[0];
    float* out  = (float*)d_out;
    float* part = (float*)d_ws;          // [2*C_CLS][NBLK] fp32 = 1.2 MB

    main_pass<<<NBLK, 256, 0, stream>>>(x, part);
    finalize<<<1, 1024, 0, stream>>>(part, out);
}